// Round 4
// baseline (9057.635 us; speedup 1.0000x reference)
//
#include <hip/hip_runtime.h>

constexpr int NUM_USERS = 100000;
constexpr int NUM_ITEMS = 50000;
constexpr int DIM = 64;
constexpr int NNZ_R = 3200000;
constexpr int NNZ_S = 2000000;

constexpr int BROWS = 32;                                // rows per bucket
constexpr int BSH = 5;                                   // log2(BROWS)
constexpr int NB_U = (NUM_USERS + BROWS - 1) / BROWS;    // 3125
constexpr int NB_I = (NUM_ITEMS + BROWS - 1) / BROWS;    // 1563

// ---- bucket histograms (counts land at P+1 so the same array becomes bucket-ptr) ----
__global__ void hist_all(const int* __restrict__ rr, const int* __restrict__ rc,
                         const int* __restrict__ sr, int* __restrict__ cntU,
                         int* __restrict__ cntI, int* __restrict__ cntS) {
    int i0 = blockIdx.x * blockDim.x + threadIdx.x;
    int st = gridDim.x * blockDim.x;
    for (int i = i0; i < NNZ_R; i += st) {
        atomicAdd(&cntU[rr[i] >> BSH], 1);
        atomicAdd(&cntI[rc[i] >> BSH], 1);
    }
    for (int i = i0; i < NNZ_S; i += st) {
        atomicAdd(&cntS[sr[i] >> BSH], 1);
    }
}

// ---- 3 independent single-block exclusive scans in one dispatch ----
struct ScanArr { int* P; int n; };

__global__ __launch_bounds__(1024) void exscan3(ScanArr a0, ScanArr a1, ScanArr a2) {
    ScanArr A = (blockIdx.x == 0) ? a0 : (blockIdx.x == 1) ? a1 : a2;
    int* buf = A.P + 1;
    int n = A.n;
    __shared__ int part[1024];
    int t = threadIdx.x;
    int chunk = (n + 1023) >> 10;
    int lo = t * chunk, hi = min(lo + chunk, n);
    int s = 0;
    for (int i = lo; i < hi; ++i) s += buf[i];
    part[t] = s;
    __syncthreads();
    for (int off = 1; off < 1024; off <<= 1) {
        int v = (t >= off) ? part[t - off] : 0;
        __syncthreads();
        part[t] += v;
        __syncthreads();
    }
    int excl = (t == 0) ? 0 : part[t - 1];
    for (int i = lo; i < hi; ++i) {
        int c = buf[i];
        buf[i] = excl;   // exclusive start (becomes cursor, then end-ptr)
        excl += c;
    }
    if (t == 0) A.P[0] = 0;
}

// ---- bin passes: append (local_row<<17 | col, val_bits) to coarse buckets ----
__global__ void bin_r(const int* __restrict__ rows, const int* __restrict__ cols,
                      const float* __restrict__ vals, int* __restrict__ curU,
                      int* __restrict__ curI, int2* __restrict__ entU,
                      int2* __restrict__ entI) {
    int i = blockIdx.x * blockDim.x + threadIdx.x;
    int st = gridDim.x * blockDim.x;
    for (; i < NNZ_R; i += st) {
        int r = rows[i], c = cols[i];
        int v = __float_as_int(vals[i]);
        int pu = atomicAdd(&curU[r >> BSH], 1);
        int pi = atomicAdd(&curI[c >> BSH], 1);
        entU[pu] = make_int2(((r & (BROWS - 1)) << 17) | c, v);
        entI[pi] = make_int2(((c & (BROWS - 1)) << 17) | r, v);
    }
}

__global__ void bin_s(const int* __restrict__ rows, const int* __restrict__ cols,
                      const float* __restrict__ vals, int* __restrict__ cur,
                      int2* __restrict__ ent) {
    int i = blockIdx.x * blockDim.x + threadIdx.x;
    int st = gridDim.x * blockDim.x;
    for (; i < NNZ_S; i += st) {
        int r = rows[i];
        int pos = atomicAdd(&cur[r >> BSH], 1);
        ent[pos] = make_int2(((r & (BROWS - 1)) << 17) | cols[i], __float_as_int(vals[i]));
    }
}

// ---- bucketed SpMM: one block per 32-row bucket, LDS f32 accumulator tile,
//      one wave per edge (broadcast entry + coalesced 256B gather + ds_add),
//      fused weighted accumulate into acc on writeout. ----
struct BOp {
    const int* P;      // NB+1 bucket ptrs (post-bin cursor values)
    const int2* ent;
    const float* x;
    float* out;        // may be nullptr (acc-only)
    float* acc;
    float w;
    int nrows;
};

__global__ __launch_bounds__(256) void spmm_bucket(BOp A, BOp B, int ablocks) {
    __shared__ float lds[BROWS * DIM];
    bool isA = (int)blockIdx.x < ablocks;
    BOp op = isA ? A : B;
    int b = isA ? blockIdx.x : blockIdx.x - ablocks;
    int tid = threadIdx.x;
    int wave = tid >> 6, d = tid & 63;
    #pragma unroll
    for (int i = tid; i < BROWS * DIM; i += 256) lds[i] = 0.f;
    __syncthreads();
    int e0 = op.P[b], e1 = op.P[b + 1];
    const int2* __restrict__ ent = op.ent;
    const float* __restrict__ x = op.x;
    int e = e0 + wave;
    for (; e + 12 < e1; e += 16) {   // 4 edges in flight per wave
        int2 n0 = ent[e], n1 = ent[e + 4], n2 = ent[e + 8], n3 = ent[e + 12];
        float x0 = x[(size_t)(n0.x & 0x1FFFF) * DIM + d];
        float x1 = x[(size_t)(n1.x & 0x1FFFF) * DIM + d];
        float x2 = x[(size_t)(n2.x & 0x1FFFF) * DIM + d];
        float x3 = x[(size_t)(n3.x & 0x1FFFF) * DIM + d];
        atomicAdd(&lds[(n0.x >> 17) * DIM + d], __int_as_float(n0.y) * x0);
        atomicAdd(&lds[(n1.x >> 17) * DIM + d], __int_as_float(n1.y) * x1);
        atomicAdd(&lds[(n2.x >> 17) * DIM + d], __int_as_float(n2.y) * x2);
        atomicAdd(&lds[(n3.x >> 17) * DIM + d], __int_as_float(n3.y) * x3);
    }
    for (; e < e1; e += 4) {
        int2 n0 = ent[e];
        float xv = x[(size_t)(n0.x & 0x1FFFF) * DIM + d];
        atomicAdd(&lds[(n0.x >> 17) * DIM + d], __int_as_float(n0.y) * xv);
    }
    __syncthreads();
    int rowbase = b * BROWS;
    for (int r = wave; r < BROWS; r += 4) {
        int grow = rowbase + r;
        if (grow >= op.nrows) break;
        float sum = lds[r * DIM + d];
        size_t idx = (size_t)grow * DIM + d;
        if (op.out) op.out[idx] = sum;
        op.acc[idx] += op.w * sum;
    }
}

// acc_u = (0.6/4 + 0.4/3)*user_emb ; acc_i = 0.25*item_emb
__global__ void init_acc(const float* __restrict__ ue, const float* __restrict__ ie,
                         float* __restrict__ accU, float* __restrict__ accI,
                         int u4, int i4) {
    const float wu = 0.6f / 4.0f + 0.4f / 3.0f;
    const float wi = 0.25f;
    int i = blockIdx.x * blockDim.x + threadIdx.x;
    int st = gridDim.x * blockDim.x;
    int n4 = u4 + i4;
    for (; i < n4; i += st) {
        if (i < u4) {
            float4 v = reinterpret_cast<const float4*>(ue)[i];
            reinterpret_cast<float4*>(accU)[i] = make_float4(wu * v.x, wu * v.y, wu * v.z, wu * v.w);
        } else {
            int j = i - u4;
            float4 v = reinterpret_cast<const float4*>(ie)[j];
            reinterpret_cast<float4*>(accI)[j] = make_float4(wi * v.x, wi * v.y, wi * v.z, wi * v.w);
        }
    }
}

__global__ void finalize_kernel(float* __restrict__ out, int nrows) {
    int row = blockIdx.x * 4 + (threadIdx.x >> 6);
    if (row >= nrows) return;
    int d = threadIdx.x & 63;
    int idx = row * DIM + d;
    float val = out[idx];
    float sq = val * val;
    #pragma unroll
    for (int off = 32; off; off >>= 1) sq += __shfl_xor(sq, off, 64);
    out[idx] = val / fmaxf(sqrtf(sq), 1e-12f);
}

extern "C" void kernel_launch(void* const* d_in, const int* in_sizes, int n_in,
                              void* d_out, int out_size, void* d_ws, size_t ws_size,
                              hipStream_t stream) {
    const float* user_emb = (const float*)d_in[0];
    const float* item_emb = (const float*)d_in[1];
    const float* r_vals   = (const float*)d_in[2];
    const float* s_vals   = (const float*)d_in[3];
    const int*   r_rows   = (const int*)d_in[4];
    const int*   r_cols   = (const int*)d_in[5];
    const int*   s_rows   = (const int*)d_in[6];
    const int*   s_cols   = (const int*)d_in[7];

    const size_t U = (size_t)NUM_USERS * DIM;
    const size_t I = (size_t)NUM_ITEMS * DIM;

    // workspace (~144.1 MB)
    int2* rB  = (int2*)d_ws;          // NNZ_R
    int2* rtB = rB + NNZ_R;           // NNZ_R
    int2* sB  = rtB + NNZ_R;          // NNZ_S
    float* uA = (float*)(sB + NNZ_S); // U
    float* uB = uA + U;               // U
    float* iA = uB + U;               // I
    float* iB = iA + I;               // I
    int* PU = (int*)(iB + I);         // NB_U+1  (counts -> cursor -> bucket ptr)
    int* PI = PU + NB_U + 1;          // NB_I+1
    int* PS = PI + NB_I + 1;          // NB_U+1

    float* accU = (float*)d_out;
    float* accI = (float*)d_out + U;

    dim3 blk(256);
    const int PTOT = (NB_U + 1) + (NB_I + 1) + (NB_U + 1);

    hipMemsetAsync(PU, 0, PTOT * sizeof(int), stream);
    init_acc<<<2048, blk, 0, stream>>>(user_emb, item_emb, accU, accI,
                                       (int)(U / 4), (int)(I / 4));

    // ---- build 3 binned structures in 4 dispatches ----
    hist_all<<<2048, blk, 0, stream>>>(r_rows, r_cols, s_rows, PU + 1, PI + 1, PS + 1);
    ScanArr sa0{PU, NB_U}, sa1{PI, NB_I}, sa2{PS, NB_U};
    exscan3<<<3, 1024, 0, stream>>>(sa0, sa1, sa2);
    bin_r<<<2048, blk, 0, stream>>>(r_rows, r_cols, r_vals, PU + 1, PI + 1, rB, rtB);
    bin_s<<<2048, blk, 0, stream>>>(s_rows, s_cols, s_vals, PS + 1, sB);

    // ---- 3 bipartite layers, both directions fused per dispatch ----
    const float WU = 0.6f / 4.0f, WI = 0.25f, WS = 0.4f / 3.0f;

    BOp u1{PU, rB, item_emb, uA, accU, WU, NUM_USERS};
    BOp i1{PI, rtB, user_emb, iA, accI, WI, NUM_ITEMS};
    spmm_bucket<<<NB_U + NB_I, blk, 0, stream>>>(u1, i1, NB_U);

    BOp u2{PU, rB, iA, uB, accU, WU, NUM_USERS};
    BOp i2{PI, rtB, uA, iB, accI, WI, NUM_ITEMS};
    spmm_bucket<<<NB_U + NB_I, blk, 0, stream>>>(u2, i2, NB_U);

    BOp u3{PU, rB, iB, nullptr, accU, WU, NUM_USERS};
    BOp i3{PI, rtB, uB, nullptr, accI, WI, NUM_ITEMS};
    spmm_bucket<<<NB_U + NB_I, blk, 0, stream>>>(u3, i3, NB_U);

    // ---- 2 social layers (uA free after layer 2) ----
    BOp so1{PS, sB, user_emb, uA, accU, WS, NUM_USERS};
    spmm_bucket<<<NB_U, blk, 0, stream>>>(so1, so1, NB_U);
    BOp so2{PS, sB, uA, nullptr, accU, WS, NUM_USERS};
    spmm_bucket<<<NB_U, blk, 0, stream>>>(so2, so2, NB_U);

    finalize_kernel<<<(NUM_USERS + NUM_ITEMS + 3) / 4, blk, 0, stream>>>(
        (float*)d_out, NUM_USERS + NUM_ITEMS);
}

// Round 6
// 1776.104 us; speedup vs baseline: 5.0997x; 5.0997x over previous
//
#include <hip/hip_runtime.h>

constexpr int NUM_USERS = 100000;
constexpr int NUM_ITEMS = 50000;
constexpr int DIM = 64;
constexpr int NNZ_R = 3200000;
constexpr int NNZ_S = 2000000;

constexpr int BSH_U = 5, BROWS_U = 32;      // user buckets: 32 rows
constexpr int BSH_I = 4, BROWS_I = 16;      // item buckets: 16 rows (same ~1024 mean entries)
constexpr int NB_U = NUM_USERS / BROWS_U;   // 3125 (exact)
constexpr int NB_I = NUM_ITEMS / BROWS_I;   // 3125 (exact)

// ---- bucket histograms (counts at P+1 so the array becomes bucket ptrs after scan) ----
__global__ void hist_all(const int* __restrict__ rr, const int* __restrict__ rc,
                         const int* __restrict__ sr, int* __restrict__ cntU,
                         int* __restrict__ cntI, int* __restrict__ cntS) {
    int i0 = blockIdx.x * blockDim.x + threadIdx.x;
    int st = gridDim.x * blockDim.x;
    for (int i = i0; i < NNZ_R; i += st) {
        atomicAdd(&cntU[rr[i] >> BSH_U], 1);
        atomicAdd(&cntI[rc[i] >> BSH_I], 1);
    }
    for (int i = i0; i < NNZ_S; i += st) atomicAdd(&cntS[sr[i] >> BSH_U], 1);
}

// ---- 3 independent single-block exclusive scans ----
struct ScanArr { int* P; int n; };

__global__ __launch_bounds__(1024) void exscan3(ScanArr a0, ScanArr a1, ScanArr a2) {
    ScanArr A = (blockIdx.x == 0) ? a0 : (blockIdx.x == 1) ? a1 : a2;
    int* buf = A.P + 1;
    int n = A.n;
    __shared__ int part[1024];
    int t = threadIdx.x;
    int chunk = (n + 1023) >> 10;
    int lo = t * chunk, hi = min(lo + chunk, n);
    int s = 0;
    for (int i = lo; i < hi; ++i) s += buf[i];
    part[t] = s;
    __syncthreads();
    for (int off = 1; off < 1024; off <<= 1) {
        int v = (t >= off) ? part[t - off] : 0;
        __syncthreads();
        part[t] += v;
        __syncthreads();
    }
    int excl = (t == 0) ? 0 : part[t - 1];
    for (int i = lo; i < hi; ++i) {
        int c = buf[i];
        buf[i] = excl;
        excl += c;
    }
    if (t == 0) A.P[0] = 0;
}

// ---- coarse bin: append (local_row<<17 | col, val_bits); frontier lines stay hot in L2 ----
__global__ void bin_all(const int* __restrict__ rr, const int* __restrict__ rc,
                        const float* __restrict__ rv, const int* __restrict__ sr,
                        const int* __restrict__ sc, const float* __restrict__ sv,
                        int* __restrict__ curU, int* __restrict__ curI,
                        int* __restrict__ curS, int2* __restrict__ binR,
                        int2* __restrict__ binRT, int2* __restrict__ binS) {
    int i0 = blockIdx.x * blockDim.x + threadIdx.x;
    int st = gridDim.x * blockDim.x;
    for (int i = i0; i < NNZ_R; i += st) {
        int r = rr[i], c = rc[i];
        int v = __float_as_int(rv[i]);
        int pu = atomicAdd(&curU[r >> BSH_U], 1);
        int pi = atomicAdd(&curI[c >> BSH_I], 1);
        binR[pu]  = make_int2(((r & (BROWS_U - 1)) << 17) | c, v);
        binRT[pi] = make_int2(((c & (BROWS_I - 1)) << 17) | r, v);
    }
    for (int i = i0; i < NNZ_S; i += st) {
        int r = sr[i];
        int pos = atomicAdd(&curS[r >> BSH_U], 1);
        binS[pos] = make_int2(((r & (BROWS_U - 1)) << 17) | sc[i], __float_as_int(sv[i]));
    }
}

// ---- per-bucket counting sort: binned -> row-sorted CSR entries + global rowptr.
//      Two streaming reads of the bucket; writes confined to the bucket's own
//      ~8KB contiguous window (L2 write-combines, full lines). ----
struct SortOp {
    const int2* src;   // binned entries
    int2* dst;         // sorted (col,val) entries
    const int* P;      // nb+1 bucket ptrs
    int* rowptr;       // nrows+1
    int brows;         // rows per bucket
    int nb;
    int nrows;
};

__global__ __launch_bounds__(256) void sort_buckets(SortOp A, SortOp B, SortOp C,
                                                    int na, int nab) {
    int gb = blockIdx.x;
    SortOp op = (gb < na) ? A : (gb < nab) ? B : C;
    int b = (gb < na) ? gb : (gb < nab) ? gb - na : gb - nab;
    int tid = threadIdx.x;
    __shared__ int cnt[32];
    __shared__ int ofs[32];
    if (tid < 32) cnt[tid] = 0;
    __syncthreads();
    int b0 = op.P[b], b1 = op.P[b + 1];
    // pass 1: count local rows
    for (int i = b0 + tid; i < b1; i += 256)
        atomicAdd(&cnt[(unsigned)op.src[i].x >> 17], 1);
    __syncthreads();
    if (tid == 0) {
        int run = 0;
        for (int r = 0; r < 32; ++r) { ofs[r] = run; run += cnt[r]; }
    }
    __syncthreads();
    if (tid < op.brows) op.rowptr[b * op.brows + tid] = b0 + ofs[tid];
    if (b == op.nb - 1 && tid == 0) op.rowptr[op.nrows] = b1;
    __syncthreads();   // rowptr must be published before pass 2 mutates ofs (race fix)
    // pass 2: scatter into sorted positions (ofs doubles as cursor)
    for (int i = b0 + tid; i < b1; i += 256) {
        int2 v = op.src[i];
        int lr = (unsigned)v.x >> 17;
        int pos = b0 + atomicAdd(&ofs[lr], 1);
        op.dst[pos] = make_int2(v.x & 0x1FFFF, v.y);
    }
}

// ---- CSR SpMM: one row per wave, 8 register-accumulated gathers in flight,
//      fused weighted accumulate; two independent ops per dispatch ----
struct SpmmOp {
    const int* rowptr;
    const int2* ent;   // (col, val_bits)
    const float* x;
    float* out;        // may be nullptr (acc-only)
    float* acc;
    float w;
    int nrows;
};

__global__ __launch_bounds__(256, 4) void spmm2(SpmmOp A, SpmmOp B, int ablocks) {
    bool isA = (int)blockIdx.x < ablocks;
    SpmmOp op = isA ? A : B;
    int bid = isA ? blockIdx.x : blockIdx.x - ablocks;
    int row = bid * 4 + (threadIdx.x >> 6);
    if (row >= op.nrows) return;
    int d = threadIdx.x & 63;
    const int2* __restrict__ ent = op.ent;
    const float* __restrict__ x = op.x;
    int e = op.rowptr[row], end = op.rowptr[row + 1];
    float s0 = 0.f, s1 = 0.f, s2 = 0.f, s3 = 0.f, s4 = 0.f, s5 = 0.f, s6 = 0.f, s7 = 0.f;
    for (; e + 8 <= end; e += 8) {
        int2 e0 = ent[e],     e1 = ent[e + 1], e2 = ent[e + 2], e3 = ent[e + 3];
        int2 e4 = ent[e + 4], e5 = ent[e + 5], e6 = ent[e + 6], e7 = ent[e + 7];
        float x0 = x[(size_t)e0.x * DIM + d];
        float x1 = x[(size_t)e1.x * DIM + d];
        float x2 = x[(size_t)e2.x * DIM + d];
        float x3 = x[(size_t)e3.x * DIM + d];
        float x4 = x[(size_t)e4.x * DIM + d];
        float x5 = x[(size_t)e5.x * DIM + d];
        float x6 = x[(size_t)e6.x * DIM + d];
        float x7 = x[(size_t)e7.x * DIM + d];
        s0 += __int_as_float(e0.y) * x0;
        s1 += __int_as_float(e1.y) * x1;
        s2 += __int_as_float(e2.y) * x2;
        s3 += __int_as_float(e3.y) * x3;
        s4 += __int_as_float(e4.y) * x4;
        s5 += __int_as_float(e5.y) * x5;
        s6 += __int_as_float(e6.y) * x6;
        s7 += __int_as_float(e7.y) * x7;
    }
    for (; e < end; ++e) {
        int2 t = ent[e];
        s0 += __int_as_float(t.y) * x[(size_t)t.x * DIM + d];
    }
    float sum = ((s0 + s1) + (s2 + s3)) + ((s4 + s5) + (s6 + s7));
    size_t idx = (size_t)row * DIM + d;
    if (op.out) op.out[idx] = sum;
    op.acc[idx] += op.w * sum;
}

// acc_u = (0.6/4 + 0.4/3)*user_emb ; acc_i = 0.25*item_emb
__global__ void init_acc(const float* __restrict__ ue, const float* __restrict__ ie,
                         float* __restrict__ accU, float* __restrict__ accI,
                         int u4, int i4) {
    const float wu = 0.6f / 4.0f + 0.4f / 3.0f;
    const float wi = 0.25f;
    int i = blockIdx.x * blockDim.x + threadIdx.x;
    int st = gridDim.x * blockDim.x;
    int n4 = u4 + i4;
    for (; i < n4; i += st) {
        if (i < u4) {
            float4 v = reinterpret_cast<const float4*>(ue)[i];
            reinterpret_cast<float4*>(accU)[i] = make_float4(wu * v.x, wu * v.y, wu * v.z, wu * v.w);
        } else {
            int j = i - u4;
            float4 v = reinterpret_cast<const float4*>(ie)[j];
            reinterpret_cast<float4*>(accI)[j] = make_float4(wi * v.x, wi * v.y, wi * v.z, wi * v.w);
        }
    }
}

__global__ void finalize_kernel(float* __restrict__ out, int nrows) {
    int row = blockIdx.x * 4 + (threadIdx.x >> 6);
    if (row >= nrows) return;
    int d = threadIdx.x & 63;
    int idx = row * DIM + d;
    float val = out[idx];
    float sq = val * val;
    #pragma unroll
    for (int off = 32; off; off >>= 1) sq += __shfl_xor(sq, off, 64);
    out[idx] = val / fmaxf(sqrtf(sq), 1e-12f);
}

extern "C" void kernel_launch(void* const* d_in, const int* in_sizes, int n_in,
                              void* d_out, int out_size, void* d_ws, size_t ws_size,
                              hipStream_t stream) {
    const float* user_emb = (const float*)d_in[0];
    const float* item_emb = (const float*)d_in[1];
    const float* r_vals   = (const float*)d_in[2];
    const float* s_vals   = (const float*)d_in[3];
    const int*   r_rows   = (const int*)d_in[4];
    const int*   r_cols   = (const int*)d_in[5];
    const int*   s_rows   = (const int*)d_in[6];
    const int*   s_cols   = (const int*)d_in[7];

    const size_t U = (size_t)NUM_USERS * DIM;
    const size_t I = (size_t)NUM_ITEMS * DIM;

    // ---- workspace (~145.1 MB) ----
    int2* sortR  = (int2*)d_ws;           // NNZ_R sorted CSR entries
    int2* sortRT = sortR + NNZ_R;         // NNZ_R
    int2* sortS  = sortRT + NNZ_R;        // NNZ_S
    float* uA = (float*)(sortS + NNZ_S);  // dense region: U+U+I+I floats (76.8 MB)
    float* uB = uA + U;
    float* iA = uB + U;
    float* iB = iA + I;
    // binned entries alias the dense region (dead before first dense write)
    int2* binR  = (int2*)uA;              // NNZ_R   (25.6 MB)
    int2* binRT = binR + NNZ_R;           // NNZ_R   (25.6)
    int2* binS  = binRT + NNZ_R;          // NNZ_S   (16)  -> 67.2 <= 76.8 OK
    int* PU  = (int*)(iB + I);            // NB_U+1 bucket ptrs
    int* PI  = PU + NB_U + 1;             // NB_I+1
    int* PS  = PI + NB_I + 1;             // NB_U+1
    int* rPu = PS + NB_U + 1;             // NUM_USERS+1 rowptr
    int* rPi = rPu + NUM_USERS + 1;       // NUM_ITEMS+1
    int* rPs = rPi + NUM_ITEMS + 1;       // NUM_USERS+1

    float* accU = (float*)d_out;
    float* accI = (float*)d_out + U;

    dim3 blk(256);
    const int PTOT = (NB_U + 1) + (NB_I + 1) + (NB_U + 1);

    hipMemsetAsync(PU, 0, PTOT * sizeof(int), stream);
    init_acc<<<2048, blk, 0, stream>>>(user_emb, item_emb, accU, accI,
                                       (int)(U / 4), (int)(I / 4));

    // ---- build: hist -> scan -> bin -> per-bucket counting sort ----
    hist_all<<<2048, blk, 0, stream>>>(r_rows, r_cols, s_rows, PU + 1, PI + 1, PS + 1);
    ScanArr sa0{PU, NB_U}, sa1{PI, NB_I}, sa2{PS, NB_U};
    exscan3<<<3, 1024, 0, stream>>>(sa0, sa1, sa2);
    bin_all<<<2048, blk, 0, stream>>>(r_rows, r_cols, r_vals, s_rows, s_cols, s_vals,
                                      PU + 1, PI + 1, PS + 1, binR, binRT, binS);
    SortOp soA{binR,  sortR,  PU, rPu, BROWS_U, NB_U, NUM_USERS};
    SortOp soB{binRT, sortRT, PI, rPi, BROWS_I, NB_I, NUM_ITEMS};
    SortOp soC{binS,  sortS,  PS, rPs, BROWS_U, NB_U, NUM_USERS};
    sort_buckets<<<NB_U + NB_I + NB_U, blk, 0, stream>>>(soA, soB, soC, NB_U, NB_U + NB_I);

    // ---- 3 bipartite layers, both directions fused per dispatch ----
    const float WU = 0.6f / 4.0f, WI = 0.25f, WS = 0.4f / 3.0f;
    int ub = (NUM_USERS + 3) / 4, ib = (NUM_ITEMS + 3) / 4;

    SpmmOp u1{rPu, sortR, item_emb, uA, accU, WU, NUM_USERS};
    SpmmOp i1{rPi, sortRT, user_emb, iA, accI, WI, NUM_ITEMS};
    spmm2<<<ub + ib, blk, 0, stream>>>(u1, i1, ub);

    SpmmOp u2{rPu, sortR, iA, uB, accU, WU, NUM_USERS};
    SpmmOp i2{rPi, sortRT, uA, iB, accI, WI, NUM_ITEMS};
    spmm2<<<ub + ib, blk, 0, stream>>>(u2, i2, ub);

    SpmmOp u3{rPu, sortR, iB, nullptr, accU, WU, NUM_USERS};
    SpmmOp i3{rPi, sortRT, uB, nullptr, accI, WI, NUM_ITEMS};
    spmm2<<<ub + ib, blk, 0, stream>>>(u3, i3, ub);

    // ---- 2 social layers (uA dead after layer 2 -> reuse) ----
    SpmmOp so1{rPs, sortS, user_emb, uA, accU, WS, NUM_USERS};
    spmm2<<<ub, blk, 0, stream>>>(so1, so1, ub);
    SpmmOp so2{rPs, sortS, uA, nullptr, accU, WS, NUM_USERS};
    spmm2<<<ub, blk, 0, stream>>>(so2, so2, ub);

    finalize_kernel<<<(NUM_USERS + NUM_ITEMS + 3) / 4, blk, 0, stream>>>(
        (float*)d_out, NUM_USERS + NUM_ITEMS);
}

// Round 7
// 1093.166 us; speedup vs baseline: 8.2857x; 1.6247x over previous
//
#include <hip/hip_runtime.h>

constexpr int NUM_USERS = 100000;
constexpr int NUM_ITEMS = 50000;
constexpr int DIM = 64;
constexpr int NNZ_R = 3200000;
constexpr int NNZ_S = 2000000;
constexpr int NNZ_TOT = NNZ_R + NNZ_R + NNZ_S;   // 8.4M entries, one array

constexpr int BSH_U = 5, BROWS_U = 32;      // user buckets: 32 rows
constexpr int BSH_I = 4, BROWS_I = 16;      // item buckets: 16 rows
constexpr int NC_U = NUM_USERS / BROWS_U;   // 3125
constexpr int NC_I = NUM_ITEMS / BROWS_I;   // 3125
constexpr int NC_S = NC_U;                  // 3125
constexpr int NC = NC_U + NC_I + NC_S;      // 9375 unified counters
constexpr int NBLK = 256;                   // build blocks (1 chunk each)
constexpr int CHUNK_R = NNZ_R / NBLK;       // 12500 exact
constexpr int CHUNK_S = (NNZ_S + NBLK - 1) / NBLK;  // 7813

// ---- pass A: LDS-privatized histogram into unified counters at P+1 ----
__global__ __launch_bounds__(1024) void hist_lds(const int* __restrict__ rr,
                                                 const int* __restrict__ rc,
                                                 const int* __restrict__ sr,
                                                 int* __restrict__ cnt /* = P+1, zeroed */) {
    __shared__ int lds[NC];
    int k = blockIdx.x, tid = threadIdx.x;
    for (int c = tid; c < NC; c += 1024) lds[c] = 0;
    __syncthreads();
    int r0 = k * CHUNK_R, r1 = r0 + CHUNK_R;
    int s0 = k * CHUNK_S, s1 = min(s0 + CHUNK_S, NNZ_S);
    for (int i = r0 + tid; i < r1; i += 1024) {
        atomicAdd(&lds[rr[i] >> BSH_U], 1);
        atomicAdd(&lds[NC_U + (rc[i] >> BSH_I)], 1);
    }
    for (int i = s0 + tid; i < s1; i += 1024)
        atomicAdd(&lds[NC_U + NC_I + (sr[i] >> BSH_U)], 1);
    __syncthreads();
    for (int c = tid; c < NC; c += 1024) {
        int n = lds[c];
        if (n) atomicAdd(&cnt[c], n);
    }
}

// ---- single-block exclusive scan over NC counts at P+1 (in place); P[0]=0 ----
__global__ __launch_bounds__(1024) void exscan1(int* __restrict__ P) {
    int* buf = P + 1;
    __shared__ int part[1024];
    int t = threadIdx.x;
    const int chunk = (NC + 1023) >> 10;
    int lo = t * chunk, hi = min(lo + chunk, NC);
    int s = 0;
    for (int i = lo; i < hi; ++i) s += buf[i];
    part[t] = s;
    __syncthreads();
    for (int off = 1; off < 1024; off <<= 1) {
        int v = (t >= off) ? part[t - off] : 0;
        __syncthreads();
        part[t] += v;
        __syncthreads();
    }
    int excl = (t == 0) ? 0 : part[t - 1];
    for (int i = lo; i < hi; ++i) {
        int c = buf[i];
        buf[i] = excl;
        excl += c;
    }
    if (t == 0) P[0] = 0;
}

// ---- pass B: re-hist in LDS, block-reserve global space, scatter via LDS cursors.
//      cur = P+1: after all reservations+bumps, P becomes the bucket-ptr array. ----
__global__ __launch_bounds__(1024) void bin_pass(const int* __restrict__ rr,
                                                 const int* __restrict__ rc,
                                                 const float* __restrict__ rv,
                                                 const int* __restrict__ sr,
                                                 const int* __restrict__ sc,
                                                 const float* __restrict__ sv,
                                                 int* __restrict__ cur /* = P+1 */,
                                                 int2* __restrict__ ent) {
    __shared__ int lds[NC];
    int k = blockIdx.x, tid = threadIdx.x;
    for (int c = tid; c < NC; c += 1024) lds[c] = 0;
    __syncthreads();
    int r0 = k * CHUNK_R, r1 = r0 + CHUNK_R;
    int s0 = k * CHUNK_S, s1 = min(s0 + CHUNK_S, NNZ_S);
    // phase 1: local histogram of this block's chunk
    for (int i = r0 + tid; i < r1; i += 1024) {
        atomicAdd(&lds[rr[i] >> BSH_U], 1);
        atomicAdd(&lds[NC_U + (rc[i] >> BSH_I)], 1);
    }
    for (int i = s0 + tid; i < s1; i += 1024)
        atomicAdd(&lds[NC_U + NC_I + (sr[i] >> BSH_U)], 1);
    __syncthreads();
    // phase 2: reserve contiguous global space per (block, bucket)
    for (int c = tid; c < NC; c += 1024) {
        int n = lds[c];
        lds[c] = n ? atomicAdd(&cur[c], n) : 0;
    }
    __syncthreads();
    // phase 3: scatter entries via LDS cursor bumps (no global atomics)
    for (int i = r0 + tid; i < r1; i += 1024) {
        int r = rr[i], c = rc[i];
        int v = __float_as_int(rv[i]);
        int pu = atomicAdd(&lds[r >> BSH_U], 1);
        ent[pu] = make_int2(((r & (BROWS_U - 1)) << 17) | c, v);
        int pi = atomicAdd(&lds[NC_U + (c >> BSH_I)], 1);
        ent[pi] = make_int2(((c & (BROWS_I - 1)) << 17) | r, v);
    }
    for (int i = s0 + tid; i < s1; i += 1024) {
        int r = sr[i];
        int ps = atomicAdd(&lds[NC_U + NC_I + (r >> BSH_U)], 1);
        ent[ps] = make_int2(((r & (BROWS_U - 1)) << 17) | sc[i], __float_as_int(sv[i]));
    }
}

// ---- per-bucket counting sort: binned -> row-sorted entries + global rowptr ----
__global__ __launch_bounds__(256) void sort_buckets(const int2* __restrict__ src,
                                                    int2* __restrict__ dst,
                                                    const int* __restrict__ P,
                                                    int* __restrict__ rPu,
                                                    int* __restrict__ rPi,
                                                    int* __restrict__ rPs) {
    int gb = blockIdx.x;   // 0..NC-1
    int* rowptr;
    int brows, lb;
    if (gb < NC_U)              { rowptr = rPu; brows = BROWS_U; lb = gb; }
    else if (gb < NC_U + NC_I)  { rowptr = rPi; brows = BROWS_I; lb = gb - NC_U; }
    else                        { rowptr = rPs; brows = BROWS_U; lb = gb - NC_U - NC_I; }
    int tid = threadIdx.x;
    __shared__ int cnt[32];
    __shared__ int ofs[32];
    if (tid < 32) cnt[tid] = 0;
    __syncthreads();
    int b0 = P[gb], b1 = P[gb + 1];
    for (int i = b0 + tid; i < b1; i += 256)
        atomicAdd(&cnt[(unsigned)src[i].x >> 17], 1);
    __syncthreads();
    if (tid == 0) {
        int run = 0;
        for (int r = 0; r < 32; ++r) { ofs[r] = run; run += cnt[r]; }
    }
    __syncthreads();
    if (tid < brows) rowptr[lb * brows + tid] = b0 + ofs[tid];
    if (gb == 0 && tid == 0) {
        rPu[NUM_USERS] = NNZ_R;
        rPi[NUM_ITEMS] = 2 * NNZ_R;
        rPs[NUM_USERS] = NNZ_TOT;
    }
    __syncthreads();   // rowptr published before pass 2 mutates ofs
    for (int i = b0 + tid; i < b1; i += 256) {
        int2 v = src[i];
        int lr = (unsigned)v.x >> 17;
        int pos = b0 + atomicAdd(&ofs[lr], 1);
        dst[pos] = make_int2(v.x & 0x1FFFF, v.y);
    }
}

// ---- CSR SpMM: one row per wave, 8 register-accumulated gathers in flight,
//      fused weighted accumulate; two independent ops per dispatch ----
struct SpmmOp {
    const int* rowptr;   // global offsets into the shared sorted entry array
    const int2* ent;
    const float* x;
    float* out;          // may be nullptr (acc-only)
    float* acc;
    float w;
    int nrows;
};

__global__ __launch_bounds__(256, 4) void spmm2(SpmmOp A, SpmmOp B, int ablocks) {
    bool isA = (int)blockIdx.x < ablocks;
    SpmmOp op = isA ? A : B;
    int bid = isA ? blockIdx.x : blockIdx.x - ablocks;
    int row = bid * 4 + (threadIdx.x >> 6);
    if (row >= op.nrows) return;
    int d = threadIdx.x & 63;
    const int2* __restrict__ ent = op.ent;
    const float* __restrict__ x = op.x;
    int e = op.rowptr[row], end = op.rowptr[row + 1];
    float s0 = 0.f, s1 = 0.f, s2 = 0.f, s3 = 0.f, s4 = 0.f, s5 = 0.f, s6 = 0.f, s7 = 0.f;
    for (; e + 8 <= end; e += 8) {
        int2 e0 = ent[e],     e1 = ent[e + 1], e2 = ent[e + 2], e3 = ent[e + 3];
        int2 e4 = ent[e + 4], e5 = ent[e + 5], e6 = ent[e + 6], e7 = ent[e + 7];
        float x0 = x[(size_t)e0.x * DIM + d];
        float x1 = x[(size_t)e1.x * DIM + d];
        float x2 = x[(size_t)e2.x * DIM + d];
        float x3 = x[(size_t)e3.x * DIM + d];
        float x4 = x[(size_t)e4.x * DIM + d];
        float x5 = x[(size_t)e5.x * DIM + d];
        float x6 = x[(size_t)e6.x * DIM + d];
        float x7 = x[(size_t)e7.x * DIM + d];
        s0 += __int_as_float(e0.y) * x0;
        s1 += __int_as_float(e1.y) * x1;
        s2 += __int_as_float(e2.y) * x2;
        s3 += __int_as_float(e3.y) * x3;
        s4 += __int_as_float(e4.y) * x4;
        s5 += __int_as_float(e5.y) * x5;
        s6 += __int_as_float(e6.y) * x6;
        s7 += __int_as_float(e7.y) * x7;
    }
    for (; e < end; ++e) {
        int2 t = ent[e];
        s0 += __int_as_float(t.y) * x[(size_t)t.x * DIM + d];
    }
    float sum = ((s0 + s1) + (s2 + s3)) + ((s4 + s5) + (s6 + s7));
    size_t idx = (size_t)row * DIM + d;
    if (op.out) op.out[idx] = sum;
    op.acc[idx] += op.w * sum;
}

// acc_u = (0.6/4 + 0.4/3)*user_emb ; acc_i = 0.25*item_emb
__global__ void init_acc(const float* __restrict__ ue, const float* __restrict__ ie,
                         float* __restrict__ accU, float* __restrict__ accI,
                         int u4, int i4) {
    const float wu = 0.6f / 4.0f + 0.4f / 3.0f;
    const float wi = 0.25f;
    int i = blockIdx.x * blockDim.x + threadIdx.x;
    int st = gridDim.x * blockDim.x;
    int n4 = u4 + i4;
    for (; i < n4; i += st) {
        if (i < u4) {
            float4 v = reinterpret_cast<const float4*>(ue)[i];
            reinterpret_cast<float4*>(accU)[i] = make_float4(wu * v.x, wu * v.y, wu * v.z, wu * v.w);
        } else {
            int j = i - u4;
            float4 v = reinterpret_cast<const float4*>(ie)[j];
            reinterpret_cast<float4*>(accI)[j] = make_float4(wi * v.x, wi * v.y, wi * v.z, wi * v.w);
        }
    }
}

__global__ void finalize_kernel(float* __restrict__ out, int nrows) {
    int row = blockIdx.x * 4 + (threadIdx.x >> 6);
    if (row >= nrows) return;
    int d = threadIdx.x & 63;
    int idx = row * DIM + d;
    float val = out[idx];
    float sq = val * val;
    #pragma unroll
    for (int off = 32; off; off >>= 1) sq += __shfl_xor(sq, off, 64);
    out[idx] = val / fmaxf(sqrtf(sq), 1e-12f);
}

extern "C" void kernel_launch(void* const* d_in, const int* in_sizes, int n_in,
                              void* d_out, int out_size, void* d_ws, size_t ws_size,
                              hipStream_t stream) {
    const float* user_emb = (const float*)d_in[0];
    const float* item_emb = (const float*)d_in[1];
    const float* r_vals   = (const float*)d_in[2];
    const float* s_vals   = (const float*)d_in[3];
    const int*   r_rows   = (const int*)d_in[4];
    const int*   r_cols   = (const int*)d_in[5];
    const int*   s_rows   = (const int*)d_in[6];
    const int*   s_cols   = (const int*)d_in[7];

    const size_t U = (size_t)NUM_USERS * DIM;
    const size_t I = (size_t)NUM_ITEMS * DIM;

    // ---- workspace (~145.1 MB) ----
    int2* ent_sorted = (int2*)d_ws;               // NNZ_TOT (67.2 MB), persistent
    float* uA = (float*)(ent_sorted + NNZ_TOT);   // dense region 76.8 MB
    float* uB = uA + U;
    float* iA = uB + U;
    float* iB = iA + I;
    int2* ent_bin = (int2*)uA;                    // NNZ_TOT (67.2 MB), aliased: dead
                                                  // before first dense write (layer 1)
    int* P   = (int*)(iB + I);                    // NC+1 unified bucket ptrs
    int* rPu = P + NC + 1;                        // NUM_USERS+1 rowptr (global offsets)
    int* rPi = rPu + NUM_USERS + 1;               // NUM_ITEMS+1
    int* rPs = rPi + NUM_ITEMS + 1;               // NUM_USERS+1

    float* accU = (float*)d_out;
    float* accI = (float*)d_out + U;

    dim3 blk(256);

    hipMemsetAsync(P, 0, (NC + 1) * sizeof(int), stream);
    init_acc<<<2048, blk, 0, stream>>>(user_emb, item_emb, accU, accI,
                                       (int)(U / 4), (int)(I / 4));

    // ---- build: LDS hist -> scan -> reserve+scatter -> per-bucket sort ----
    hist_lds<<<NBLK, 1024, 0, stream>>>(r_rows, r_cols, s_rows, P + 1);
    exscan1<<<1, 1024, 0, stream>>>(P);
    bin_pass<<<NBLK, 1024, 0, stream>>>(r_rows, r_cols, r_vals, s_rows, s_cols, s_vals,
                                        P + 1, ent_bin);
    sort_buckets<<<NC, blk, 0, stream>>>(ent_bin, ent_sorted, P, rPu, rPi, rPs);

    // ---- 3 bipartite layers, both directions fused per dispatch ----
    const float WU = 0.6f / 4.0f, WI = 0.25f, WS = 0.4f / 3.0f;
    int ub = (NUM_USERS + 3) / 4, ib = (NUM_ITEMS + 3) / 4;

    SpmmOp u1{rPu, ent_sorted, item_emb, uA, accU, WU, NUM_USERS};
    SpmmOp i1{rPi, ent_sorted, user_emb, iA, accI, WI, NUM_ITEMS};
    spmm2<<<ub + ib, blk, 0, stream>>>(u1, i1, ub);

    SpmmOp u2{rPu, ent_sorted, iA, uB, accU, WU, NUM_USERS};
    SpmmOp i2{rPi, ent_sorted, uA, iB, accI, WI, NUM_ITEMS};
    spmm2<<<ub + ib, blk, 0, stream>>>(u2, i2, ub);

    SpmmOp u3{rPu, ent_sorted, iB, nullptr, accU, WU, NUM_USERS};
    SpmmOp i3{rPi, ent_sorted, uB, nullptr, accI, WI, NUM_ITEMS};
    spmm2<<<ub + ib, blk, 0, stream>>>(u3, i3, ub);

    // ---- 2 social layers (uA dead after layer 2 -> reuse) ----
    SpmmOp so1{rPs, ent_sorted, user_emb, uA, accU, WS, NUM_USERS};
    spmm2<<<ub, blk, 0, stream>>>(so1, so1, ub);
    SpmmOp so2{rPs, ent_sorted, uA, nullptr, accU, WS, NUM_USERS};
    spmm2<<<ub, blk, 0, stream>>>(so2, so2, ub);

    finalize_kernel<<<(NUM_USERS + NUM_ITEMS + 3) / 4, blk, 0, stream>>>(
        (float*)d_out, NUM_USERS + NUM_ITEMS);
}

// Round 8
// 965.475 us; speedup vs baseline: 9.3815x; 1.1323x over previous
//
#include <hip/hip_runtime.h>

constexpr int NUM_USERS = 100000;
constexpr int NUM_ITEMS = 50000;
constexpr int DIM = 64;
constexpr int NNZ_R = 3200000;
constexpr int NNZ_S = 2000000;
constexpr int NNZ_TOT = NNZ_R + NNZ_R + NNZ_S;   // 8.4M entries, one array

constexpr int BSH_U = 5, BROWS_U = 32;      // user buckets: 32 rows
constexpr int BSH_I = 4, BROWS_I = 16;      // item buckets: 16 rows
constexpr int NC_U = NUM_USERS / BROWS_U;   // 3125
constexpr int NC_I = NUM_ITEMS / BROWS_I;   // 3125
constexpr int NC_S = NC_U;                  // 3125
constexpr int NC = NC_U + NC_I + NC_S;      // 9375 unified counters
constexpr int NBLK = 256;
constexpr int CHUNK_R = NNZ_R / NBLK;       // 12500 exact
constexpr int CHUNK_S = (NNZ_S + NBLK - 1) / NBLK;  // 7813

__device__ __forceinline__ float bf2f(unsigned short u) {
    return __uint_as_float((unsigned)u << 16);
}
__device__ __forceinline__ unsigned short f2bf(float f) {   // round-to-nearest-even
    unsigned u = __float_as_uint(f);
    return (unsigned short)((u + 0x7FFFu + ((u >> 16) & 1u)) >> 16);
}

// ---- pass A: LDS-privatized histogram into unified counters at P+1 ----
__global__ __launch_bounds__(1024) void hist_lds(const int* __restrict__ rr,
                                                 const int* __restrict__ rc,
                                                 const int* __restrict__ sr,
                                                 int* __restrict__ cnt /* = P+1, zeroed */) {
    __shared__ int lds[NC];
    int k = blockIdx.x, tid = threadIdx.x;
    for (int c = tid; c < NC; c += 1024) lds[c] = 0;
    __syncthreads();
    int r0 = k * CHUNK_R, r1 = r0 + CHUNK_R;
    int s0 = k * CHUNK_S, s1 = min(s0 + CHUNK_S, NNZ_S);
    for (int i = r0 + tid; i < r1; i += 1024) {
        atomicAdd(&lds[rr[i] >> BSH_U], 1);
        atomicAdd(&lds[NC_U + (rc[i] >> BSH_I)], 1);
    }
    for (int i = s0 + tid; i < s1; i += 1024)
        atomicAdd(&lds[NC_U + NC_I + (sr[i] >> BSH_U)], 1);
    __syncthreads();
    for (int c = tid; c < NC; c += 1024) {
        int n = lds[c];
        if (n) atomicAdd(&cnt[c], n);
    }
}

// ---- single-block exclusive scan over NC counts at P+1 (in place); P[0]=0 ----
__global__ __launch_bounds__(1024) void exscan1(int* __restrict__ P) {
    int* buf = P + 1;
    __shared__ int part[1024];
    int t = threadIdx.x;
    const int chunk = (NC + 1023) >> 10;
    int lo = t * chunk, hi = min(lo + chunk, NC);
    int s = 0;
    for (int i = lo; i < hi; ++i) s += buf[i];
    part[t] = s;
    __syncthreads();
    for (int off = 1; off < 1024; off <<= 1) {
        int v = (t >= off) ? part[t - off] : 0;
        __syncthreads();
        part[t] += v;
        __syncthreads();
    }
    int excl = (t == 0) ? 0 : part[t - 1];
    for (int i = lo; i < hi; ++i) {
        int c = buf[i];
        buf[i] = excl;
        excl += c;
    }
    if (t == 0) P[0] = 0;
}

// ---- pass B: re-hist in LDS, block-reserve global space, scatter via LDS cursors ----
__global__ __launch_bounds__(1024) void bin_pass(const int* __restrict__ rr,
                                                 const int* __restrict__ rc,
                                                 const float* __restrict__ rv,
                                                 const int* __restrict__ sr,
                                                 const int* __restrict__ sc,
                                                 const float* __restrict__ sv,
                                                 int* __restrict__ cur /* = P+1 */,
                                                 int2* __restrict__ ent) {
    __shared__ int lds[NC];
    int k = blockIdx.x, tid = threadIdx.x;
    for (int c = tid; c < NC; c += 1024) lds[c] = 0;
    __syncthreads();
    int r0 = k * CHUNK_R, r1 = r0 + CHUNK_R;
    int s0 = k * CHUNK_S, s1 = min(s0 + CHUNK_S, NNZ_S);
    for (int i = r0 + tid; i < r1; i += 1024) {
        atomicAdd(&lds[rr[i] >> BSH_U], 1);
        atomicAdd(&lds[NC_U + (rc[i] >> BSH_I)], 1);
    }
    for (int i = s0 + tid; i < s1; i += 1024)
        atomicAdd(&lds[NC_U + NC_I + (sr[i] >> BSH_U)], 1);
    __syncthreads();
    for (int c = tid; c < NC; c += 1024) {
        int n = lds[c];
        lds[c] = n ? atomicAdd(&cur[c], n) : 0;
    }
    __syncthreads();
    for (int i = r0 + tid; i < r1; i += 1024) {
        int r = rr[i], c = rc[i];
        int v = __float_as_int(rv[i]);
        int pu = atomicAdd(&lds[r >> BSH_U], 1);
        ent[pu] = make_int2(((r & (BROWS_U - 1)) << 17) | c, v);
        int pi = atomicAdd(&lds[NC_U + (c >> BSH_I)], 1);
        ent[pi] = make_int2(((c & (BROWS_I - 1)) << 17) | r, v);
    }
    for (int i = s0 + tid; i < s1; i += 1024) {
        int r = sr[i];
        int ps = atomicAdd(&lds[NC_U + NC_I + (r >> BSH_U)], 1);
        ent[ps] = make_int2(((r & (BROWS_U - 1)) << 17) | sc[i], __float_as_int(sv[i]));
    }
}

// ---- per-bucket counting sort: binned -> row-sorted entries + global rowptr ----
__global__ __launch_bounds__(256) void sort_buckets(const int2* __restrict__ src,
                                                    int2* __restrict__ dst,
                                                    const int* __restrict__ P,
                                                    int* __restrict__ rPu,
                                                    int* __restrict__ rPi,
                                                    int* __restrict__ rPs) {
    int gb = blockIdx.x;
    int* rowptr;
    int brows, lb;
    if (gb < NC_U)              { rowptr = rPu; brows = BROWS_U; lb = gb; }
    else if (gb < NC_U + NC_I)  { rowptr = rPi; brows = BROWS_I; lb = gb - NC_U; }
    else                        { rowptr = rPs; brows = BROWS_U; lb = gb - NC_U - NC_I; }
    int tid = threadIdx.x;
    __shared__ int cnt[32];
    __shared__ int ofs[32];
    if (tid < 32) cnt[tid] = 0;
    __syncthreads();
    int b0 = P[gb], b1 = P[gb + 1];
    for (int i = b0 + tid; i < b1; i += 256)
        atomicAdd(&cnt[(unsigned)src[i].x >> 17], 1);
    __syncthreads();
    if (tid == 0) {
        int run = 0;
        for (int r = 0; r < 32; ++r) { ofs[r] = run; run += cnt[r]; }
    }
    __syncthreads();
    if (tid < brows) rowptr[lb * brows + tid] = b0 + ofs[tid];
    if (gb == 0 && tid == 0) {
        rPu[NUM_USERS] = NNZ_R;
        rPi[NUM_ITEMS] = 2 * NNZ_R;
        rPs[NUM_USERS] = NNZ_TOT;
    }
    __syncthreads();
    for (int i = b0 + tid; i < b1; i += 256) {
        int2 v = src[i];
        int lr = (unsigned)v.x >> 17;
        int pos = b0 + atomicAdd(&ofs[lr], 1);
        dst[pos] = make_int2(v.x & 0x1FFFF, v.y);
    }
}

// ---- CSR SpMM over bf16 operand rows: one row per wave, 8 gathers in flight,
//      f32 register accumulation, fused f32 weighted acc; bf16 out for next layer ----
struct SpmmOp {
    const int* rowptr;          // global offsets into the shared sorted entry array
    const int2* ent;
    const unsigned short* x;    // bf16 rows [nrows_x][64]
    unsigned short* out;        // bf16, may be nullptr (acc-only)
    float* acc;
    float w;
    int nrows;
};

__global__ __launch_bounds__(256, 4) void spmm2(SpmmOp A, SpmmOp B, int ablocks) {
    bool isA = (int)blockIdx.x < ablocks;
    SpmmOp op = isA ? A : B;
    int bid = isA ? blockIdx.x : blockIdx.x - ablocks;
    int row = bid * 4 + (threadIdx.x >> 6);
    if (row >= op.nrows) return;
    int d = threadIdx.x & 63;
    const int2* __restrict__ ent = op.ent;
    const unsigned short* __restrict__ x = op.x;
    int e = op.rowptr[row], end = op.rowptr[row + 1];
    float s0 = 0.f, s1 = 0.f, s2 = 0.f, s3 = 0.f, s4 = 0.f, s5 = 0.f, s6 = 0.f, s7 = 0.f;
    for (; e + 8 <= end; e += 8) {
        int2 e0 = ent[e],     e1 = ent[e + 1], e2 = ent[e + 2], e3 = ent[e + 3];
        int2 e4 = ent[e + 4], e5 = ent[e + 5], e6 = ent[e + 6], e7 = ent[e + 7];
        float x0 = bf2f(x[(size_t)e0.x * DIM + d]);
        float x1 = bf2f(x[(size_t)e1.x * DIM + d]);
        float x2 = bf2f(x[(size_t)e2.x * DIM + d]);
        float x3 = bf2f(x[(size_t)e3.x * DIM + d]);
        float x4 = bf2f(x[(size_t)e4.x * DIM + d]);
        float x5 = bf2f(x[(size_t)e5.x * DIM + d]);
        float x6 = bf2f(x[(size_t)e6.x * DIM + d]);
        float x7 = bf2f(x[(size_t)e7.x * DIM + d]);
        s0 += __int_as_float(e0.y) * x0;
        s1 += __int_as_float(e1.y) * x1;
        s2 += __int_as_float(e2.y) * x2;
        s3 += __int_as_float(e3.y) * x3;
        s4 += __int_as_float(e4.y) * x4;
        s5 += __int_as_float(e5.y) * x5;
        s6 += __int_as_float(e6.y) * x6;
        s7 += __int_as_float(e7.y) * x7;
    }
    for (; e < end; ++e) {
        int2 t = ent[e];
        s0 += __int_as_float(t.y) * bf2f(x[(size_t)t.x * DIM + d]);
    }
    float sum = ((s0 + s1) + (s2 + s3)) + ((s4 + s5) + (s6 + s7));
    size_t idx = (size_t)row * DIM + d;
    if (op.out) op.out[idx] = f2bf(sum);
    op.acc[idx] += op.w * sum;
}

// acc init + bf16 copies of the input embeddings (runs AFTER the build so the
// bf16 dense region may alias ent_bin).
__global__ void init_acc(const float* __restrict__ ue, const float* __restrict__ ie,
                         float* __restrict__ accU, float* __restrict__ accI,
                         unsigned short* __restrict__ ueB, unsigned short* __restrict__ ieB,
                         int u4, int i4) {
    const float wu = 0.6f / 4.0f + 0.4f / 3.0f;
    const float wi = 0.25f;
    int i = blockIdx.x * blockDim.x + threadIdx.x;
    int st = gridDim.x * blockDim.x;
    int n4 = u4 + i4;
    for (; i < n4; i += st) {
        if (i < u4) {
            float4 v = reinterpret_cast<const float4*>(ue)[i];
            reinterpret_cast<float4*>(accU)[i] = make_float4(wu * v.x, wu * v.y, wu * v.z, wu * v.w);
            ushort4 b;
            b.x = f2bf(v.x); b.y = f2bf(v.y); b.z = f2bf(v.z); b.w = f2bf(v.w);
            reinterpret_cast<ushort4*>(ueB)[i] = b;
        } else {
            int j = i - u4;
            float4 v = reinterpret_cast<const float4*>(ie)[j];
            reinterpret_cast<float4*>(accI)[j] = make_float4(wi * v.x, wi * v.y, wi * v.z, wi * v.w);
            ushort4 b;
            b.x = f2bf(v.x); b.y = f2bf(v.y); b.z = f2bf(v.z); b.w = f2bf(v.w);
            reinterpret_cast<ushort4*>(ieB)[j] = b;
        }
    }
}

__global__ void finalize_kernel(float* __restrict__ out, int nrows) {
    int row = blockIdx.x * 4 + (threadIdx.x >> 6);
    if (row >= nrows) return;
    int d = threadIdx.x & 63;
    int idx = row * DIM + d;
    float val = out[idx];
    float sq = val * val;
    #pragma unroll
    for (int off = 32; off; off >>= 1) sq += __shfl_xor(sq, off, 64);
    out[idx] = val / fmaxf(sqrtf(sq), 1e-12f);
}

extern "C" void kernel_launch(void* const* d_in, const int* in_sizes, int n_in,
                              void* d_out, int out_size, void* d_ws, size_t ws_size,
                              hipStream_t stream) {
    const float* user_emb = (const float*)d_in[0];
    const float* item_emb = (const float*)d_in[1];
    const float* r_vals   = (const float*)d_in[2];
    const float* s_vals   = (const float*)d_in[3];
    const int*   r_rows   = (const int*)d_in[4];
    const int*   r_cols   = (const int*)d_in[5];
    const int*   s_rows   = (const int*)d_in[6];
    const int*   s_cols   = (const int*)d_in[7];

    const size_t U = (size_t)NUM_USERS * DIM;
    const size_t I = (size_t)NUM_ITEMS * DIM;

    // ---- workspace (~135.5 MB) ----
    int2* ent_sorted = (int2*)d_ws;                       // NNZ_TOT (67.2 MB), persistent
    char* region2 = (char*)(ent_sorted + NNZ_TOT);        // 67.2 MB union:
    int2* ent_bin = (int2*)region2;                       //   build-time: NNZ_TOT entries
    unsigned short* ueB = (unsigned short*)region2;       //   spmm-time: bf16 dense (57.6 MB)
    unsigned short* ieB = ueB + U;
    unsigned short* uA  = ieB + I;
    unsigned short* uB  = uA + U;
    unsigned short* iA  = uB + U;
    unsigned short* iB  = iA + I;
    int* P   = (int*)(region2 + (size_t)NNZ_TOT * 8);     // NC+1 bucket ptrs
    int* rPu = P + NC + 1;
    int* rPi = rPu + NUM_USERS + 1;
    int* rPs = rPi + NUM_ITEMS + 1;

    float* accU = (float*)d_out;
    float* accI = (float*)d_out + U;

    dim3 blk(256);

    hipMemsetAsync(P, 0, (NC + 1) * sizeof(int), stream);

    // ---- build first (ent_bin occupies region2), then convert/init ----
    hist_lds<<<NBLK, 1024, 0, stream>>>(r_rows, r_cols, s_rows, P + 1);
    exscan1<<<1, 1024, 0, stream>>>(P);
    bin_pass<<<NBLK, 1024, 0, stream>>>(r_rows, r_cols, r_vals, s_rows, s_cols, s_vals,
                                        P + 1, ent_bin);
    sort_buckets<<<NC, blk, 0, stream>>>(ent_bin, ent_sorted, P, rPu, rPi, rPs);

    init_acc<<<2048, blk, 0, stream>>>(user_emb, item_emb, accU, accI, ueB, ieB,
                                       (int)(U / 4), (int)(I / 4));

    // ---- 3 bipartite layers, both directions fused per dispatch ----
    const float WU = 0.6f / 4.0f, WI = 0.25f, WS = 0.4f / 3.0f;
    int ub = (NUM_USERS + 3) / 4, ib = (NUM_ITEMS + 3) / 4;

    SpmmOp u1{rPu, ent_sorted, ieB, uA, accU, WU, NUM_USERS};
    SpmmOp i1{rPi, ent_sorted, ueB, iA, accI, WI, NUM_ITEMS};
    spmm2<<<ub + ib, blk, 0, stream>>>(u1, i1, ub);

    SpmmOp u2{rPu, ent_sorted, iA, uB, accU, WU, NUM_USERS};
    SpmmOp i2{rPi, ent_sorted, uA, iB, accI, WI, NUM_ITEMS};
    spmm2<<<ub + ib, blk, 0, stream>>>(u2, i2, ub);

    SpmmOp u3{rPu, ent_sorted, iB, nullptr, accU, WU, NUM_USERS};
    SpmmOp i3{rPi, ent_sorted, uB, nullptr, accI, WI, NUM_ITEMS};
    spmm2<<<ub + ib, blk, 0, stream>>>(u3, i3, ub);

    // ---- 2 social layers (uA dead after layer 2 -> reuse as social ping) ----
    SpmmOp so1{rPs, ent_sorted, ueB, uA, accU, WS, NUM_USERS};
    spmm2<<<ub, blk, 0, stream>>>(so1, so1, ub);
    SpmmOp so2{rPs, ent_sorted, uA, nullptr, accU, WS, NUM_USERS};
    spmm2<<<ub, blk, 0, stream>>>(so2, so2, ub);

    finalize_kernel<<<(NUM_USERS + NUM_ITEMS + 3) / 4, blk, 0, stream>>>(
        (float*)d_out, NUM_USERS + NUM_ITEMS);
}